// Round 5
// baseline (134.714 us; speedup 1.0000x reference)
//
#include <hip/hip_runtime.h>

#define Bn 4096
#define NF 20
#define NEMB 16
#define HIDN 512
#define KE 16
#define GIN 320
#define NKS 10   // K-steps of 32

typedef __attribute__((ext_vector_type(8))) short short8;
typedef __attribute__((ext_vector_type(4))) float f32x4;

__device__ __forceinline__ unsigned short f2bf(float f) {
  unsigned int u = __builtin_bit_cast(unsigned int, f);
  u += 0x7fff + ((u >> 16) & 1);
  return (unsigned short)(u >> 16);
}
__device__ __forceinline__ float bf2f(unsigned short h) {
  unsigned int u = ((unsigned int)h) << 16;
  return __builtin_bit_cast(float, u);
}

// ---------------- prep: gathers, bf16 conversion, fragment-ordered weights --
__global__ __launch_bounds__(256) void prep_kernel(
    const int* __restrict__ x, const int* __restrict__ sql,
    const float* __restrict__ demb, const float* __restrict__ semb,
    const float* __restrict__ gw1, const float* __restrict__ ew1,
    unsigned short* __restrict__ XE, unsigned short* __restrict__ SH,
    unsigned short* __restrict__ SL, unsigned short* __restrict__ GWF,
    unsigned short* __restrict__ EWF, float* __restrict__ y,
    int* __restrict__ cnt) {
  long long t = (long long)blockIdx.x * 256 + threadIdx.x;
  if (t < 81920) {
    int row = (int)(t / NF), f = (int)(t % NF);
    int idx = x[row * NF + f];
    const float* s = demb + (size_t)idx * NEMB;
    short8 o0, o1;
#pragma unroll
    for (int i = 0; i < 8; i++) {
      o0[i] = (short)f2bf(s[i]);
      o1[i] = (short)f2bf(s[8 + i]);
    }
    size_t o = (size_t)row * GIN + f * NEMB;
    *(short8*)(XE + o) = o0;
    *(short8*)(XE + o + 8) = o1;
    return;
  }
  t -= 81920;
  if (t < 81920) {
    int row = (int)(t / NF), f = (int)(t % NF);
    int idx = sql[row * NF + f];
    const float* s = semb + (size_t)idx * NEMB;
    short8 h0, h1, l0, l1;
#pragma unroll
    for (int i = 0; i < 8; i++) {
      float v = s[i];
      unsigned short hb = f2bf(v);
      h0[i] = (short)hb; l0[i] = (short)f2bf(v - bf2f(hb));
      v = s[8 + i];
      hb = f2bf(v);
      h1[i] = (short)hb; l1[i] = (short)f2bf(v - bf2f(hb));
    }
    size_t o = (size_t)row * GIN + f * NEMB;
    *(short8*)(SH + o) = h0; *(short8*)(SH + o + 8) = h1;
    *(short8*)(SL + o) = l0; *(short8*)(SL + o + 8) = l1;
    return;
  }
  t -= 81920;
  if (t < 40960) {
    int s = (int)(t / 20480), r = (int)(t % 20480);
    int ks = r / 2048, r2 = r % 2048, nt = r2 / 64, l = r2 % 64;
    int k0 = ks * 32 + (l >> 4) * 8, n = nt * 16 + (l & 15);
    short8 o;
#pragma unroll
    for (int j = 0; j < 8; j++) {
      float w = gw1[(size_t)(k0 + j) * HIDN + n];
      unsigned short hb = f2bf(w);
      o[j] = (s == 0) ? (short)hb : (short)f2bf(w - bf2f(hb));
    }
    *(short8*)(GWF + ((((size_t)s * NKS + ks) * 32 + nt) * 64 + l) * 8) = o;
    return;
  }
  t -= 40960;
  if (t < 327680) {
    int e = (int)(t / 20480), r = (int)(t % 20480);
    int ks = r / 2048, r2 = r % 2048, nt = r2 / 64, l = r2 % 64;
    int k0 = ks * 32 + (l >> 4) * 8, n = nt * 16 + (l & 15);
    const float* W = ew1 + (size_t)e * GIN * HIDN;
    short8 o;
#pragma unroll
    for (int j = 0; j < 8; j++) o[j] = (short)f2bf(W[(size_t)(k0 + j) * HIDN + n]);
    *(short8*)(EWF + ((((size_t)e * NKS + ks) * 32 + nt) * 64 + l) * 8) = o;
    return;
  }
  t -= 327680;
  if (t < Bn + 1) y[t] = 0.f;
  else if (t < Bn + 1 + KE) cnt[t - (Bn + 1)] = 0;
}

// ---------------- gate: split-bf16 MFMA, register-streamed B ----------------
// grid (256 rowgroups, 4 col-blocks of 128); no K-loop barriers.
__global__ __launch_bounds__(256) void gate_kernel(
    const unsigned short* __restrict__ SH, const unsigned short* __restrict__ SL,
    const unsigned short* __restrict__ GWF, const float* __restrict__ gb1,
    const float* __restrict__ gw2, float* __restrict__ glp) {
  __shared__ float hs[16][132];          // +4 pad: 2-way banks in logits loop
  __shared__ __align__(16) float g2s[128][16];
  const int tid = threadIdx.x, lane = tid & 63, wv = tid >> 6;
  const int row0 = blockIdx.x * 16, nb = blockIdx.y;

  // stage this col-block's gw2 slice (contiguous 8 KB)
  {
    const float4* src = (const float4*)(gw2 + (size_t)nb * 128 * KE);
    float4* dst = (float4*)g2s;
    for (int p = tid; p < 512; p += 256) dst[p] = src[p];
  }

  const size_t rr = (size_t)(row0 + (lane & 15)) * GIN;
  const int ko = (lane >> 4) * 8;
  const unsigned short* Gh = GWF + ((size_t)(nb * 8 + wv * 2)) * 512 + lane * 8;
  const unsigned short* Gl = Gh + (size_t)NKS * 32 * 512;
  f32x4 acc[2] = {};
#pragma unroll
  for (int ks = 0; ks < NKS; ks++) {
    short8 ah = *(const short8*)(SH + rr + ks * 32 + ko);
    short8 al = *(const short8*)(SL + rr + ks * 32 + ko);
    const size_t so = (size_t)ks * 32 * 512;
    short8 bh0 = *(const short8*)(Gh + so);
    short8 bh1 = *(const short8*)(Gh + so + 512);
    short8 bl0 = *(const short8*)(Gl + so);
    short8 bl1 = *(const short8*)(Gl + so + 512);
    acc[0] = __builtin_amdgcn_mfma_f32_16x16x32_bf16(ah, bh0, acc[0], 0, 0, 0);
    acc[0] = __builtin_amdgcn_mfma_f32_16x16x32_bf16(al, bh0, acc[0], 0, 0, 0);
    acc[0] = __builtin_amdgcn_mfma_f32_16x16x32_bf16(ah, bl0, acc[0], 0, 0, 0);
    acc[1] = __builtin_amdgcn_mfma_f32_16x16x32_bf16(ah, bh1, acc[1], 0, 0, 0);
    acc[1] = __builtin_amdgcn_mfma_f32_16x16x32_bf16(al, bh1, acc[1], 0, 0, 0);
    acc[1] = __builtin_amdgcn_mfma_f32_16x16x32_bf16(ah, bl1, acc[1], 0, 0, 0);
  }

  // bias + relu -> hs
#pragma unroll
  for (int nt = 0; nt < 2; nt++) {
    int cl = (wv * 2 + nt) * 16 + (lane & 15);
    float b = gb1[nb * 128 + cl];
#pragma unroll
    for (int j = 0; j < 4; j++)
      hs[(lane >> 4) * 4 + j][cl] = fmaxf(acc[nt][j] + b, 0.f);
  }
  __syncthreads();
  {
    int row = tid >> 4, q = tid & 15;
    float s = 0.f;
#pragma unroll 4
    for (int c = 0; c < 128; c++) s = fmaf(hs[row][c], g2s[c][q], s);
    glp[((size_t)nb * Bn + row0 + row) * KE + q] = s;
  }
}

// ---------------- gate2: sum partials, softmax, top-2, bucket ---------------
__global__ __launch_bounds__(256) void gate2_kernel(
    const float* __restrict__ glp, const float* __restrict__ gb2,
    int* __restrict__ cnt, int* __restrict__ list, float* __restrict__ wlist) {
  __shared__ int lcnt[KE];
  __shared__ int gbase[KE];
  const int tid = threadIdx.x;
  const int row = blockIdx.x * 256 + tid;
  if (tid < KE) lcnt[tid] = 0;
  __syncthreads();
  float lg[KE];
  {
    const float4* c = (const float4*)gb2;
#pragma unroll
    for (int u = 0; u < 4; u++) {
      float4 s = c[u];
      lg[u * 4 + 0] = s.x; lg[u * 4 + 1] = s.y;
      lg[u * 4 + 2] = s.z; lg[u * 4 + 3] = s.w;
    }
#pragma unroll
    for (int sl = 0; sl < 4; sl++) {
      const float4* a = (const float4*)(glp + ((size_t)sl * Bn + row) * KE);
#pragma unroll
      for (int u = 0; u < 4; u++) {
        float4 v = a[u];
        lg[u * 4 + 0] += v.x; lg[u * 4 + 1] += v.y;
        lg[u * 4 + 2] += v.z; lg[u * 4 + 3] += v.w;
      }
    }
  }
  float m = lg[0];
#pragma unroll
  for (int q = 1; q < KE; q++) m = fmaxf(m, lg[q]);
  float e[KE];
#pragma unroll
  for (int q = 0; q < KE; q++) e[q] = expf(lg[q] - m);
  int i1 = 0; float v1 = e[0];
#pragma unroll
  for (int q = 1; q < KE; q++) if (e[q] > v1) { v1 = e[q]; i1 = q; }
  int i2 = (i1 == 0) ? 1 : 0; float v2 = e[i2];
#pragma unroll
  for (int q = 0; q < KE; q++)
    if (q != i1 && e[q] > v2) { v2 = e[q]; i2 = q; }
  int o1 = atomicAdd(&lcnt[i1], 1);
  int o2 = atomicAdd(&lcnt[i2], 1);
  __syncthreads();
  if (tid < KE) gbase[tid] = atomicAdd(&cnt[tid], lcnt[tid]);
  __syncthreads();
  float den = v1 + v2;
  int s1 = gbase[i1] + o1;
  list[i1 * Bn + s1] = row; wlist[i1 * Bn + s1] = v1 / den;
  int s2 = gbase[i2] + o2;
  list[i2 * Bn + s2] = row; wlist[i2 * Bn + s2] = v2 / den;
}

// ---------------- experts: register-streamed B, no K-loop barriers ----------
// grid (272 chunks of 32 rows, 4 col-blocks of 128)
__global__ __launch_bounds__(256) void expert_kernel(
    const unsigned short* __restrict__ XE, const unsigned short* __restrict__ EWF,
    const float* __restrict__ eb1, const float* __restrict__ ew2,
    const float* __restrict__ eb2, const int* __restrict__ cnt,
    const int* __restrict__ list, const float* __restrict__ wlist,
    float* __restrict__ y) {
  __shared__ int rid[32];
  __shared__ float rw[32];
  const int tid = threadIdx.x, lane = tid & 63, wv = tid >> 6;
  const int item = blockIdx.x, ch = blockIdx.y;
  int k = -1, base = 0, pref = 0;
#pragma unroll
  for (int q = 0; q < KE; q++) {
    int nc = (cnt[q] + 31) >> 5;
    if (item >= pref && item < pref + nc) { k = q; base = (item - pref) * 32; }
    pref += nc;
  }
  if (k < 0) return;
  const int n = cnt[k];
  if (tid < 32) {
    int p = base + tid;
    rid[tid] = (p < n) ? list[k * Bn + p] : 0;
    rw[tid] = (p < n) ? wlist[k * Bn + p] : 0.f;
  }
  __syncthreads();
  const int ko = (lane >> 4) * 8;
  const size_t r0 = (size_t)rid[lane & 15] * GIN;
  const size_t r1 = (size_t)rid[16 + (lane & 15)] * GIN;
  const unsigned short* Wk =
      EWF + ((size_t)k * NKS * 32 + ch * 8 + wv * 2) * 512 + lane * 8;
  f32x4 acc[2][2] = {};
#pragma unroll
  for (int ks = 0; ks < NKS; ks++) {
    short8 a0 = *(const short8*)(XE + r0 + ks * 32 + ko);
    short8 a1 = *(const short8*)(XE + r1 + ks * 32 + ko);
    const size_t so = (size_t)ks * 32 * 512;
    short8 b0 = *(const short8*)(Wk + so);
    short8 b1 = *(const short8*)(Wk + so + 512);
    acc[0][0] = __builtin_amdgcn_mfma_f32_16x16x32_bf16(a0, b0, acc[0][0], 0, 0, 0);
    acc[1][0] = __builtin_amdgcn_mfma_f32_16x16x32_bf16(a1, b0, acc[1][0], 0, 0, 0);
    acc[0][1] = __builtin_amdgcn_mfma_f32_16x16x32_bf16(a0, b1, acc[0][1], 0, 0, 0);
    acc[1][1] = __builtin_amdgcn_mfma_f32_16x16x32_bf16(a1, b1, acc[1][1], 0, 0, 0);
  }
  // epilogue: bias + relu + dot w2 + reduce over 16 n-lanes + gated atomic
  float part[2][4] = {};
#pragma unroll
  for (int nt = 0; nt < 2; nt++) {
    int colg = ch * 128 + (wv * 2 + nt) * 16 + (lane & 15);
    float b1v = eb1[(size_t)k * HIDN + colg];
    float w2 = ew2[(size_t)k * HIDN + colg];
#pragma unroll
    for (int mt = 0; mt < 2; mt++)
#pragma unroll
      for (int j = 0; j < 4; j++)
        part[mt][j] += fmaxf(acc[mt][nt][j] + b1v, 0.f) * w2;
  }
#pragma unroll
  for (int off = 8; off >= 1; off >>= 1)
#pragma unroll
    for (int mt = 0; mt < 2; mt++)
#pragma unroll
      for (int j = 0; j < 4; j++)
        part[mt][j] += __shfl_xor(part[mt][j], off);
  if ((lane & 15) == 0) {
    float e2 = (ch == 0) ? eb2[k] : 0.f;
#pragma unroll
    for (int mt = 0; mt < 2; mt++)
#pragma unroll
      for (int j = 0; j < 4; j++) {
        int rl = mt * 16 + (lane >> 4) * 4 + j;
        atomicAdd(&y[rid[rl]], rw[rl] * (part[mt][j] + e2));
      }
  }
}

// ---------------- loss ------------------------------------------------------
__global__ __launch_bounds__(256) void loss_kernel(const int* __restrict__ cnt,
                                                   const float* __restrict__ wlist,
                                                   float* __restrict__ out) {
  __shared__ float simp[KE][KE];
  __shared__ float fimp[KE];
  const int tid = threadIdx.x;
  const int k = tid >> 4, g = tid & 15;
  const int n = cnt[k];
  float s = 0.f;
  for (int j = g; j < n; j += 16) s += wlist[k * Bn + j];
  simp[k][g] = s;
  __syncthreads();
  if (tid < KE) {
    float t = 0.f;
    for (int q = 0; q < KE; q++) t += simp[tid][q];
    fimp[tid] = t;
  }
  __syncthreads();
  if (tid == 0) {
    double mi = 0.0, ml = 0.0;
    for (int q = 0; q < KE; q++) { mi += fimp[q]; ml += (double)cnt[q]; }
    mi /= KE; ml /= KE;
    double vi = 0.0, vl = 0.0;
    for (int q = 0; q < KE; q++) {
      double di = fimp[q] - mi; vi += di * di;
      double dl = (double)cnt[q] - ml; vl += dl * dl;
    }
    vi /= KE; vl /= KE;
    out[Bn] = (float)(vi / (mi * mi + 1e-10) + vl / (ml * ml + 1e-10));
  }
}

extern "C" void kernel_launch(void* const* d_in, const int* in_sizes, int n_in,
                              void* d_out, int out_size, void* d_ws, size_t ws_size,
                              hipStream_t stream) {
  const int* x      = (const int*)d_in[0];
  const int* sql    = (const int*)d_in[1];
  const float* semb = (const float*)d_in[2];
  const float* demb = (const float*)d_in[3];
  const float* gw1  = (const float*)d_in[4];
  const float* gb1  = (const float*)d_in[5];
  const float* gw2  = (const float*)d_in[6];
  const float* gb2  = (const float*)d_in[7];
  const float* ew1  = (const float*)d_in[8];
  const float* eb1  = (const float*)d_in[9];
  const float* ew2  = (const float*)d_in[10];
  const float* eb2  = (const float*)d_in[11];
  float* y = (float*)d_out;

  char* ws = (char*)d_ws;
  int* cnt            = (int*)(ws);               // 64 B
  int* list           = (int*)(ws + 4096);        // 256 KB
  float* wlist        = (float*)(ws + 266240);    // 256 KB
  float* glp          = (float*)(ws + 528384);    // 1 MB (4 slices)
  unsigned short* XE  = (unsigned short*)(ws + 1576960);   // 2.62 MB
  unsigned short* SH  = (unsigned short*)(ws + 4198400);   // 2.62 MB
  unsigned short* SL  = (unsigned short*)(ws + 6819840);   // 2.62 MB
  unsigned short* GWF = (unsigned short*)(ws + 9441280);   // 655 KB
  unsigned short* EWF = (unsigned short*)(ws + 10096640);  // 5.24 MB

  prep_kernel<<<2097, 256, 0, stream>>>(x, sql, demb, semb, gw1, ew1,
                                        XE, SH, SL, GWF, EWF, y, cnt);
  gate_kernel<<<dim3(Bn / 16, 4), 256, 0, stream>>>(SH, SL, GWF, gb1, gw2, glp);
  gate2_kernel<<<Bn / 256, 256, 0, stream>>>(glp, gb2, cnt, list, wlist);
  expert_kernel<<<dim3(272, 4), 256, 0, stream>>>(XE, EWF, eb1, ew2, eb2,
                                                  cnt, list, wlist, y);
  loss_kernel<<<1, 256, 0, stream>>>(cnt, wlist, y);
}